// Round 2
// baseline (611.903 us; speedup 1.0000x reference)
//
#include <hip/hip_runtime.h>
#include <hip/hip_cooperative_groups.h>

namespace cg = cooperative_groups;

// Instant-NGP multires hash encoding fwd. N=1M, L=16, F=2, T=2^19.
// R6 (from R5 @ 258us, k_main 112us @ 34% occupancy):
//  - k_main: 16 levels -> 3 phases sharing ONE 1800-entry LDS cache
//    (worst-case per-phase corners: {14,15}<=1458, {10..13}<=1709, {0..9}<=821)
//    => LDS 36.3KB -> ~15KB => 4 -> 8 blocks/CU (wave-capped). k_main was
//    latency-bound (per-SIMD VALU issue ~15%), occupancy doubles.
//  - aux: hist/colscan/scan/scatter fused into ONE cooperative kernel
//    (256 blocks x 1024 thr, 68KB dyn LDS, 2 grid syncs, x staged once,
//    colsum scan replicated per block). Return-code checked -> falls back
//    to the R5 5-kernel path if coop launch refused.

__constant__ float c_res[16] = {
    16.f, 18.f, 21.f, 24.f, 27.f, 32.f, 36.f, 42.f,
    48.f, 55.f, 64.f, 73.f, 84.f, 97.f, 111.f, 128.f
};

#define TMASK   0x7FFFFu
#define PRIME1  2654435761u
#define PRIME2  805459861u
#define NBUCKET 4096          // 16^3 cells
#define CACHE_PH 1800         // max corners in any phase (exact bound 1709)

__device__ __forceinline__ int bucket_of(float x0, float x1, float x2) {
    // x*16 is EXACT in fp32 (power-of-2 scale), so cell membership is exact.
    int c0 = (int)(x0 * 16.f); c0 = c0 < 0 ? 0 : (c0 > 15 ? 15 : c0);
    int c1 = (int)(x1 * 16.f); c1 = c1 < 0 ? 0 : (c1 > 15 ? 15 : c1);
    int c2 = (int)(x2 * 16.f); c2 = c2 < 0 ? 0 : (c2 > 15 ? 15 : c2);
    return (c0 << 8) | (c1 << 4) | c2;
}

// ---- fused cooperative sort: hist + colscan + scan + scatter ----
// grid 256 x 1024 threads, 1 block/CU co-resident. Dynamic LDS:
//   xraw  : chunk*3 floats (<= 48 KB)
//   cur   : 4096 u32 (hist, later cursor)
//   tbl   : 1024 u32 (scan scratch)
__global__ __launch_bounds__(1024)
void k_sort(const float* __restrict__ x, unsigned* __restrict__ cnt,
            unsigned* __restrict__ base, unsigned* __restrict__ colsum,
            unsigned* __restrict__ starts, float4* __restrict__ xs, int npts)
{
    extern __shared__ char smem[];
    float*    xraw = (float*)smem;                        // 49152 B
    unsigned* cur  = (unsigned*)(smem + 49152);           // 16384 B
    unsigned* tbl  = (unsigned*)(smem + 49152 + 16384);   //  4096 B

    const int tid = threadIdx.x;
    const int blk = blockIdx.x;
    const int chunk = npts >> 8;            // host guarantees npts % 1024 == 0
    const int begin = blk * chunk;

    // ---- P1: stage chunk to LDS (float4-coalesced), histogram ----
    {
        const float4* src = (const float4*)(x + (size_t)begin * 3);
        float4* dst = (float4*)xraw;
        const int nf4 = (chunk * 3) >> 2;   // chunk % 4 == 0
        for (int i = tid; i < nf4; i += 1024) dst[i] = src[i];
    }
    for (int j = tid; j < NBUCKET; j += 1024) cur[j] = 0u;
    __syncthreads();
    for (int i = tid; i < chunk; i += 1024) {
        int b = bucket_of(xraw[3*i], xraw[3*i+1], xraw[3*i+2]);
        atomicAdd(&cur[b], 1u);             // LDS atomic
    }
    __syncthreads();
    for (int j = tid; j < NBUCKET; j += 1024)
        cnt[(size_t)blk * NBUCKET + j] = cur[j];

    __threadfence();
    cg::this_grid().sync();

    // ---- P2: column scan over the 256x4096 cnt matrix ----
    // 16 cols/block, 64 groups x 4 rows each; Hillis-Steele over groups.
    {
        int c = tid & 15, g = tid >> 4;     // c:0..15, g:0..63
        int col = blk * 16 + c;
        unsigned loc[4], s = 0;
        #pragma unroll
        for (int k = 0; k < 4; ++k) {
            unsigned v = cnt[(size_t)(g * 4 + k) * NBUCKET + col];
            loc[k] = s; s += v;
        }
        tbl[g * 16 + c] = s;
        __syncthreads();
        for (int off = 1; off < 64; off <<= 1) {
            unsigned u = (g >= off) ? tbl[(g - off) * 16 + c] : 0u;
            __syncthreads();
            tbl[g * 16 + c] += u;
            __syncthreads();
        }
        unsigned pre = tbl[g * 16 + c] - s;
        #pragma unroll
        for (int k = 0; k < 4; ++k)
            base[(size_t)(g * 4 + k) * NBUCKET + col] = pre + loc[k];
        if (g == 63) colsum[col] = pre + s;
    }

    __threadfence();
    cg::this_grid().sync();

    // ---- P3: scan colsum[4096] REPLICATED per block -> cur = starts+base ----
    {
        unsigned v0 = colsum[4*tid+0], v1 = colsum[4*tid+1];
        unsigned v2 = colsum[4*tid+2], v3 = colsum[4*tid+3];
        unsigned s = v0 + v1 + v2 + v3;
        tbl[tid] = s;
        __syncthreads();
        for (int off = 1; off < 1024; off <<= 1) {
            unsigned u = (tid >= off) ? tbl[tid - off] : 0u;
            __syncthreads();
            tbl[tid] += u;
            __syncthreads();
        }
        unsigned excl = tbl[tid] - s;
        unsigned b0 = base[(size_t)blk * NBUCKET + 4*tid + 0];
        unsigned b1 = base[(size_t)blk * NBUCKET + 4*tid + 1];
        unsigned b2 = base[(size_t)blk * NBUCKET + 4*tid + 2];
        unsigned b3 = base[(size_t)blk * NBUCKET + 4*tid + 3];
        cur[4*tid+0] = excl + b0;
        cur[4*tid+1] = excl + v0 + b1;
        cur[4*tid+2] = excl + v0 + v1 + b2;
        cur[4*tid+3] = excl + v0 + v1 + v2 + b3;
        if (blk == 0) {
            starts[4*tid+0] = excl;
            starts[4*tid+1] = excl + v0;
            starts[4*tid+2] = excl + v0 + v1;
            starts[4*tid+3] = excl + v0 + v1 + v2;
            if (tid == 1023) starts[NBUCKET] = tbl[1023];
        }
    }
    __syncthreads();

    // ---- P4: scatter sorted float4{x,y,z,bitcast(idx)} ----
    for (int i = tid; i < chunk; i += 1024) {
        float x0 = xraw[3*i], x1 = xraw[3*i+1], x2 = xraw[3*i+2];
        int b = bucket_of(x0, x1, x2);
        unsigned pos = atomicAdd(&cur[b], 1u);
        float4 v; v.x = x0; v.y = x1; v.z = x2;
        v.w = __uint_as_float((unsigned)(begin + i));
        xs[pos] = v;
    }
}

// ---- non-coop fallback sort path (R5) ----

__global__ __launch_bounds__(256)
void k_hist(const float* __restrict__ x, unsigned* __restrict__ cnt, int npts) {
    __shared__ unsigned h[NBUCKET];
    for (int i = threadIdx.x; i < NBUCKET; i += 256) h[i] = 0u;
    __syncthreads();
    int nb = gridDim.x;
    int chunk = (npts + nb - 1) / nb;
    int begin = blockIdx.x * chunk;
    int end   = begin + chunk; if (end > npts) end = npts;
    for (int i = begin + threadIdx.x; i < end; i += 256) {
        int b = bucket_of(x[3 * i], x[3 * i + 1], x[3 * i + 2]);
        atomicAdd(&h[b], 1u);
    }
    __syncthreads();
    for (int i = threadIdx.x; i < NBUCKET; i += 256)
        cnt[blockIdx.x * NBUCKET + i] = h[i];
}

template<int NBT>
__global__ __launch_bounds__(256)
void k_colscan(const unsigned* __restrict__ cnt, unsigned* __restrict__ base,
               unsigned* __restrict__ colsum) {
    const int RPG = NBT / 8;
    int col = blockIdx.x * 32 + (threadIdx.x & 31);
    int rg  = threadIdx.x >> 5;
    unsigned loc[RPG];
    unsigned s = 0;
    #pragma unroll
    for (int r = 0; r < RPG; ++r) {
        unsigned v = cnt[(size_t)(rg * RPG + r) * NBUCKET + col];
        loc[r] = s;
        s += v;
    }
    __shared__ unsigned t[8][32];
    t[rg][threadIdx.x & 31] = s;
    __syncthreads();
    unsigned pre = 0;
    for (int g = 0; g < rg; ++g) pre += t[g][threadIdx.x & 31];
    #pragma unroll
    for (int r = 0; r < RPG; ++r)
        base[(size_t)(rg * RPG + r) * NBUCKET + col] = pre + loc[r];
    if (rg == 7) colsum[col] = pre + s;
}

__global__ __launch_bounds__(1024)
void k_scan(const unsigned* __restrict__ colsum, unsigned* __restrict__ starts) {
    __shared__ unsigned tmp[1024];
    int t = threadIdx.x;
    unsigned v0 = colsum[4 * t + 0], v1 = colsum[4 * t + 1];
    unsigned v2 = colsum[4 * t + 2], v3 = colsum[4 * t + 3];
    unsigned s = v0 + v1 + v2 + v3;
    tmp[t] = s;
    __syncthreads();
    for (int off = 1; off < 1024; off <<= 1) {
        unsigned u = (t >= off) ? tmp[t - off] : 0u;
        __syncthreads();
        tmp[t] += u;
        __syncthreads();
    }
    unsigned excl = tmp[t] - s;
    starts[4 * t + 0] = excl;
    starts[4 * t + 1] = excl + v0;
    starts[4 * t + 2] = excl + v0 + v1;
    starts[4 * t + 3] = excl + v0 + v1 + v2;
    if (t == 1023) starts[4096] = tmp[1023];
}

template<int MODE>
__global__ __launch_bounds__(256)
void k_scatter(const float* __restrict__ x, const unsigned* __restrict__ base,
               const unsigned* __restrict__ starts, unsigned* __restrict__ perm,
               float4* __restrict__ xs, int npts) {
    __shared__ unsigned cur[NBUCKET];
    for (int i = threadIdx.x; i < NBUCKET; i += 256)
        cur[i] = starts[i] + base[blockIdx.x * NBUCKET + i];
    __syncthreads();
    int nb = gridDim.x;
    int chunk = (npts + nb - 1) / nb;
    int begin = blockIdx.x * chunk;
    int end   = begin + chunk; if (end > npts) end = npts;
    for (int i = begin + threadIdx.x; i < end; i += 256) {
        float x0 = x[3 * i], x1 = x[3 * i + 1], x2 = x[3 * i + 2];
        int b = bucket_of(x0, x1, x2);
        unsigned pos = atomicAdd(&cur[b], 1u);
        if constexpr (MODE == 0) {
            float4 v; v.x = x0; v.y = x1; v.z = x2;
            v.w = __uint_as_float((unsigned)i);
            xs[pos] = v;
        } else {
            perm[pos] = (unsigned)i;
        }
    }
}

// ---- main: per-cell LDS corner cache, 3 phases sharing one buffer ----
// Box per level for cell i: lo=floor((i/16)*r), hi=ceil(((i+1)/16)*r).
// i*r<=2048 is fp32-exact, /16 dyadic-exact => bounds exact; fp-mul
// monotonicity => every per-point floor/ceil coord lies in [lo,hi].
// Per-dim count n <= ceil(r/16)+2 (non-int r/16) or r/16+1 (int) =>
// phase worst cases: {14,15}=1458, {10..13}=1709, {0..9}=821 <= CACHE_PH.

template<int MODE>   // 0: sorted xs.  1: perm + scattered x
__global__ __launch_bounds__(256, 8)
void k_main(const float4* __restrict__ xs, const float* __restrict__ x,
            const unsigned* __restrict__ perm,
            const unsigned* __restrict__ starts, const float2* __restrict__ tab,
            float4* __restrict__ out4)
{
    __shared__ float2 cache[CACHE_PH];
    __shared__ int4 metaA[16];   // lo0, lo1, lo2, cbase
    __shared__ int4 metaB[16];   // n12, n2, bitcast(r), 0

    int cell = blockIdx.x;
    int startp = starts[cell], endp = starts[cell + 1];
    if (startp == endp) return;

    int ci = (cell >> 8) & 15, cj = (cell >> 4) & 15, ck = cell & 15;
    float fi0 = ci * 0.0625f, fi1 = (ci + 1) * 0.0625f;
    float fj0 = cj * 0.0625f, fj1 = (cj + 1) * 0.0625f;
    float fk0 = ck * 0.0625f, fk1 = (ck + 1) * 0.0625f;

    auto lvl = [&](int l, float a0, float a1, float a2, float& ex, float& ey) {
        int4 mA = metaA[l];
        int4 mB = metaB[l];
        float r = __int_as_float(mB.z);
        int n12 = mB.x, n2 = mB.y;
        float s0 = a0 * r, s1 = a1 * r, s2 = a2 * r;   // lone mul == numpy
        float f0 = floorf(s0), f1 = floorf(s1), f2 = floorf(s2);
        float d0 = s0 - f0, d1 = s1 - f1, d2 = s2 - f2;
        int A0 = (int)f0 - mA.x, A1 = (int)f1 - mA.y, A2 = (int)f2 - mA.z;
        // ceil(s) = floor(s) + (s != floor(s)) for s >= 0
        int e0 = (d0 != 0.f) ? n12 : 0;
        int e1 = (d1 != 0.f) ? n2  : 0;
        int e2 = (d2 != 0.f) ? 1   : 0;
        int rA = mA.w + A0 * n12 + A1 * n2 + A2;

        float2 v0 = cache[rA];                 // 000
        float2 v1 = cache[rA + e0];            // 100
        float2 v2 = cache[rA + e1];            // 010
        float2 v3 = cache[rA + e2];            // 001
        float2 v4 = cache[rA + e0 + e1];       // 110
        float2 v5 = cache[rA + e0 + e2];       // 101
        float2 v6 = cache[rA + e1 + e2];       // 011
        float2 v7 = cache[rA + e0 + e1 + e2];  // 111

        float u0 = 1.f - d0, u1 = 1.f - d1, u2 = 1.f - d2;
        float pa = u1 * u2, pb = d1 * u2, pc = u1 * d2, pe = d1 * d2;
        float w0 = u0 * pa, w1 = d0 * pa, w2 = u0 * pb, w3 = u0 * pc;
        float w4 = d0 * pb, w5 = d0 * pc, w6 = u0 * pe, w7 = d0 * pe;

        float rx = v0.x * w0, ry = v0.y * w0;
        rx += v1.x * w1;  ry += v1.y * w1;
        rx += v2.x * w2;  ry += v2.y * w2;
        rx += v3.x * w3;  ry += v3.y * w3;
        rx += v4.x * w4;  ry += v4.y * w4;
        rx += v5.x * w5;  ry += v5.y * w5;
        rx += v6.x * w6;  ry += v6.y * w6;
        rx += v7.x * w7;  ry += v7.y * w7;
        ex = rx; ey = ry;
    };

    #pragma unroll
    for (int ph = 0; ph < 3; ++ph) {
        const int llo = (ph == 0) ? 14 : (ph == 1) ? 10 : 0;
        const int lhi = (ph == 0) ? 16 : (ph == 1) ? 14 : 10;

        // -------- loader: all 256 threads, each unique corner once --------
        int cbase = 0;
        #pragma unroll 1
        for (int l = llo; l < lhi; ++l) {
            float r = c_res[l];
            int lo0 = (int)floorf(fi0 * r), hi0 = (int)ceilf(fi1 * r);
            int lo1 = (int)floorf(fj0 * r), hi1 = (int)ceilf(fj1 * r);
            int lo2 = (int)floorf(fk0 * r), hi2 = (int)ceilf(fk1 * r);
            int n0 = hi0 - lo0 + 1, n1 = hi1 - lo1 + 1, n2 = hi2 - lo2 + 1;
            int n12 = n1 * n2, tot = n0 * n12;
            for (int t = threadIdx.x; t < tot; t += 256) {
                int a = t / n12, rem = t - a * n12;
                int b = rem / n2, d = rem - b * n2;
                unsigned h = ((unsigned)(lo0 + a)
                            ^ ((unsigned)(lo1 + b) * PRIME1)
                            ^ ((unsigned)(lo2 + d) * PRIME2)) & TMASK;
                cache[cbase + t] = tab[h];
            }
            if (threadIdx.x == 0) {
                metaA[l] = make_int4(lo0, lo1, lo2, cbase);
                metaB[l] = make_int4(n12, n2, __float_as_int(r), 0);
            }
            cbase += tot;
        }
        __syncthreads();

        // -------- interp this phase's levels for all the cell's points ----
        for (int sp = startp + (int)threadIdx.x; sp < endp; sp += 256) {
            float x0, x1, x2; unsigned p;
            if constexpr (MODE == 0) {
                float4 v = xs[sp];
                x0 = v.x; x1 = v.y; x2 = v.z; p = __float_as_uint(v.w);
            } else {
                p = perm[sp];
                x0 = x[3 * p]; x1 = x[3 * p + 1]; x2 = x[3 * p + 2];
            }
            #pragma unroll 1
            for (int lp = (llo >> 1); lp < (lhi >> 1); ++lp) {
                float4 o;
                lvl(2 * lp,     x0, x1, x2, o.x, o.y);
                lvl(2 * lp + 1, x0, x1, x2, o.z, o.w);
                out4[(size_t)p * 8 + lp] = o;
            }
        }
        __syncthreads();   // cache reused by next phase's loader
    }
}

// Fallback (R1) if ws too small.
__global__ __launch_bounds__(256, 8)
void k_fallback(const float* __restrict__ x, const float2* __restrict__ tab,
                float2* __restrict__ out, int total) {
    int tid = blockIdx.x * 256 + threadIdx.x;
    if (tid >= total) return;
    int p = tid >> 4, l = tid & 15;
    float r = c_res[l];
    float s0 = x[3*p] * r, s1 = x[3*p+1] * r, s2 = x[3*p+2] * r;
    float f0 = floorf(s0), f1 = floorf(s1), f2 = floorf(s2);
    float d0 = s0 - f0, d1 = s1 - f1, d2 = s2 - f2;
    unsigned A0 = (unsigned)(int)f0, B0 = (unsigned)(int)ceilf(s0);
    unsigned A1 = (unsigned)(int)f1 * PRIME1, B1 = (unsigned)(int)ceilf(s1) * PRIME1;
    unsigned A2 = (unsigned)(int)f2 * PRIME2, B2 = (unsigned)(int)ceilf(s2) * PRIME2;
    unsigned h0=(A0^A1^A2)&TMASK, h1=(B0^A1^A2)&TMASK, h2=(A0^B1^A2)&TMASK;
    unsigned h3=(A0^A1^B2)&TMASK, h4=(B0^B1^A2)&TMASK, h5=(B0^A1^B2)&TMASK;
    unsigned h6=(A0^B1^B2)&TMASK, h7=(B0^B1^B2)&TMASK;
    float2 v0=tab[h0],v1=tab[h1],v2=tab[h2],v3=tab[h3];
    float2 v4=tab[h4],v5=tab[h5],v6=tab[h6],v7=tab[h7];
    float u0=1.f-d0,u1=1.f-d1,u2=1.f-d2;
    float ex = v0.x*(u0*u1*u2), ey = v0.y*(u0*u1*u2);
    ex += v1.x*(d0*u1*u2); ey += v1.y*(d0*u1*u2);
    ex += v2.x*(u0*d1*u2); ey += v2.y*(u0*d1*u2);
    ex += v3.x*(u0*u1*d2); ey += v3.y*(u0*u1*d2);
    ex += v4.x*(d0*d1*u2); ey += v4.y*(d0*d1*u2);
    ex += v5.x*(d0*u1*d2); ey += v5.y*(d0*u1*d2);
    ex += v6.x*(u0*d1*d2); ey += v6.y*(u0*d1*d2);
    ex += v7.x*(d0*d1*d2); ey += v7.y*(d0*d1*d2);
    float2 o; o.x = ex; o.y = ey; out[tid] = o;
}

extern "C" void kernel_launch(void* const* d_in, const int* in_sizes, int n_in,
                              void* d_out, int out_size, void* d_ws, size_t ws_size,
                              hipStream_t stream)
{
    const float*  x   = (const float*)d_in[0];
    const float2* tab = (const float2*)d_in[1];
    int npts = in_sizes[0] / 3;

    // ---- Tier A: NB=256, sorted-float4 payload (~24 MB ws) ----
    {
        const int NBA = 256;
        size_t off_cnt    = 0;
        size_t off_base   = off_cnt    + (size_t)NBA * NBUCKET * 4;   // 4 MB
        size_t off_colsum = off_base   + (size_t)NBA * NBUCKET * 4;   // 4 MB
        size_t off_starts = off_colsum + (size_t)NBUCKET * 4;
        size_t off_xs     = (off_starts + (size_t)(NBUCKET + 1) * 4 + 63)
                            & ~(size_t)63;
        size_t need       = off_xs + (size_t)npts * 16;
        if (ws_size >= need) {
            unsigned* cnt    = (unsigned*)((char*)d_ws + off_cnt);
            unsigned* base   = (unsigned*)((char*)d_ws + off_base);
            unsigned* colsum = (unsigned*)((char*)d_ws + off_colsum);
            unsigned* starts = (unsigned*)((char*)d_ws + off_starts);
            float4*   xs     = (float4*)  ((char*)d_ws + off_xs);

            bool coop_ok = false;
            // coop path needs: exact 256-way chunking, chunk%4==0 (float4
            // alignment), chunk <= 4096 (LDS stage)
            if ((npts % 1024) == 0 && (npts >> 8) <= 4096) {
                int np = npts;
                void* args[] = { (void*)&x, (void*)&cnt, (void*)&base,
                                 (void*)&colsum, (void*)&starts, (void*)&xs,
                                 (void*)&np };
                unsigned shmem = 49152u + 16384u + 4096u;   // 68 KB
                hipError_t e = hipLaunchCooperativeKernel(
                    (void*)k_sort, dim3(256), dim3(1024), args, shmem, stream);
                coop_ok = (e == hipSuccess);
            }
            if (!coop_ok) {
                k_hist        <<<NBA, 256, 0, stream>>>(x, cnt, npts);
                k_colscan<256><<<NBUCKET / 32, 256, 0, stream>>>(cnt, base, colsum);
                k_scan        <<<1, 1024, 0, stream>>>(colsum, starts);
                k_scatter<0>  <<<NBA, 256, 0, stream>>>(x, base, starts,
                                                        nullptr, xs, npts);
            }
            k_main<0>     <<<NBUCKET, 256, 0, stream>>>(xs, x, nullptr, starts,
                                                        tab, (float4*)d_out);
            return;
        }
    }

    // ---- Tier B: NB=128, perm-only (~8 MB ws) ----
    {
        const int NBB = 128;
        size_t off_cnt    = 0;
        size_t off_base   = off_cnt    + (size_t)NBB * NBUCKET * 4;   // 2 MB
        size_t off_colsum = off_base   + (size_t)NBB * NBUCKET * 4;   // 2 MB
        size_t off_starts = off_colsum + (size_t)NBUCKET * 4;
        size_t off_perm   = (off_starts + (size_t)(NBUCKET + 1) * 4 + 63)
                            & ~(size_t)63;
        size_t need       = off_perm + (size_t)npts * 4;
        if (ws_size >= need) {
            unsigned* cnt    = (unsigned*)((char*)d_ws + off_cnt);
            unsigned* base   = (unsigned*)((char*)d_ws + off_base);
            unsigned* colsum = (unsigned*)((char*)d_ws + off_colsum);
            unsigned* starts = (unsigned*)((char*)d_ws + off_starts);
            unsigned* perm   = (unsigned*)((char*)d_ws + off_perm);

            k_hist        <<<NBB, 256, 0, stream>>>(x, cnt, npts);
            k_colscan<128><<<NBUCKET / 32, 256, 0, stream>>>(cnt, base, colsum);
            k_scan        <<<1, 1024, 0, stream>>>(colsum, starts);
            k_scatter<1>  <<<NBB, 256, 0, stream>>>(x, base, starts,
                                                    perm, nullptr, npts);
            k_main<1>     <<<NBUCKET, 256, 0, stream>>>(nullptr, x, perm, starts,
                                                        tab, (float4*)d_out);
            return;
        }
    }

    // ---- fallback ----
    int total = npts * 16;
    k_fallback<<<(total + 255) / 256, 256, 0, stream>>>(
        x, tab, (float2*)d_out, total);
}

// Round 3
// 311.030 us; speedup vs baseline: 1.9673x; 1.9673x over previous
//
#include <hip/hip_runtime.h>

// Instant-NGP multires hash encoding fwd. N=1M, L=16, F=2, T=2^19.
// R7 (from R5 @ 258us; R6's 3-phase split + coop sort both regressed and are
// reverted):
//  - k_main: single-pass 16-level LDS corner cache (36.3KB) as in R5 — the
//    per-point output row (128B) is written ONCE, contiguously, by one thread
//    (R6 lesson: splitting it across phases tripled HBM write traffic).
//    Block size 256 -> 512: LDS still allows 4 blocks/CU => 32 waves/CU
//    (was 16). k_main was latency-bound; occupancy doubles, traffic equal.
//  - aux: sort stability is NOT required (payload carries original idx), so
//    cnt/base/colscan are dropped. hist (LDS+global-merge) -> scan ->
//    scatter with global atomic cursors (1M atomics over 4096 addrs,
//    2048 blocks). 5 kernels -> 3 + 16KB memset.

__constant__ float c_res[16] = {
    16.f, 18.f, 21.f, 24.f, 27.f, 32.f, 36.f, 42.f,
    48.f, 55.f, 64.f, 73.f, 84.f, 97.f, 111.f, 128.f
};

#define TMASK   0x7FFFFu
#define PRIME1  2654435761u
#define PRIME2  805459861u
#define NBUCKET 4096          // 16^3 cells
#define CACHE_N 4467          // sum over levels of max corners — exact bound

__device__ __forceinline__ int bucket_of(float x0, float x1, float x2) {
    // x*16 is EXACT in fp32 (power-of-2 scale), so cell membership is exact.
    int c0 = (int)(x0 * 16.f); c0 = c0 < 0 ? 0 : (c0 > 15 ? 15 : c0);
    int c1 = (int)(x1 * 16.f); c1 = c1 < 0 ? 0 : (c1 > 15 ? 15 : c1);
    int c2 = (int)(x2 * 16.f); c2 = c2 < 0 ? 0 : (c2 > 15 ? 15 : c2);
    return (c0 << 8) | (c1 << 4) | c2;
}

// ---- aux 1: histogram. LDS hist per block, merge via global atomics ----
__global__ __launch_bounds__(256)
void k_hist(const float* __restrict__ x, unsigned* __restrict__ hist, int npts) {
    __shared__ unsigned h[NBUCKET];
    for (int j = threadIdx.x; j < NBUCKET; j += 256) h[j] = 0u;
    __syncthreads();
    int stride = gridDim.x * 256;
    for (int i = blockIdx.x * 256 + threadIdx.x; i < npts; i += stride) {
        int b = bucket_of(x[3 * i], x[3 * i + 1], x[3 * i + 2]);
        atomicAdd(&h[b], 1u);              // LDS atomic — cheap
    }
    __syncthreads();
    for (int j = threadIdx.x; j < NBUCKET; j += 256) {
        unsigned v = h[j];
        if (v) atomicAdd(&hist[j], v);     // ~600K global atomics total
    }
}

// ---- aux 2: exclusive scan of hist[4096] -> starts[0..4096] + cursor ----
__global__ __launch_bounds__(1024)
void k_scan(const unsigned* __restrict__ hist, unsigned* __restrict__ starts,
            unsigned* __restrict__ cursor) {
    __shared__ unsigned tmp[1024];
    int t = threadIdx.x;
    unsigned v0 = hist[4 * t + 0], v1 = hist[4 * t + 1];
    unsigned v2 = hist[4 * t + 2], v3 = hist[4 * t + 3];
    unsigned s = v0 + v1 + v2 + v3;
    tmp[t] = s;
    __syncthreads();
    for (int off = 1; off < 1024; off <<= 1) {
        unsigned u = (t >= off) ? tmp[t - off] : 0u;
        __syncthreads();
        tmp[t] += u;
        __syncthreads();
    }
    unsigned excl = tmp[t] - s;
    unsigned s1 = excl + v0, s2 = s1 + v1, s3 = s2 + v2;
    starts[4 * t + 0] = excl;  cursor[4 * t + 0] = excl;
    starts[4 * t + 1] = s1;    cursor[4 * t + 1] = s1;
    starts[4 * t + 2] = s2;    cursor[4 * t + 2] = s2;
    starts[4 * t + 3] = s3;    cursor[4 * t + 3] = s3;
    if (t == 1023) starts[NBUCKET] = tmp[1023];
}

// ---- aux 3: scatter via global atomic cursors (order within bucket is
// irrelevant — payload carries the original index) ----
template<int MODE>   // 0: float4{x,y,z,bitcast(i)}  1: perm only
__global__ __launch_bounds__(256)
void k_scatter(const float* __restrict__ x, unsigned* __restrict__ cursor,
               unsigned* __restrict__ perm, float4* __restrict__ xs, int npts) {
    int stride = gridDim.x * 256;
    for (int i = blockIdx.x * 256 + threadIdx.x; i < npts; i += stride) {
        float x0 = x[3 * i], x1 = x[3 * i + 1], x2 = x[3 * i + 2];
        int b = bucket_of(x0, x1, x2);
        unsigned pos = atomicAdd(&cursor[b], 1u);
        if constexpr (MODE == 0) {
            float4 v; v.x = x0; v.y = x1; v.z = x2;
            v.w = __uint_as_float((unsigned)i);
            xs[pos] = v;
        } else {
            perm[pos] = (unsigned)i;
        }
    }
}

// ---- main: per-cell LDS corner cache, single pass over all 16 levels ----
// Box per level for cell i: lo=floor((i/16)*r), hi=ceil(((i+1)/16)*r).
// i*r<=2048 is fp32-exact, /16 dyadic-exact => bounds exact; fp-mul
// monotonicity => every per-point floor/ceil coord lies in [lo,hi].

template<int MODE>   // 0: sorted xs.  1: perm + scattered x
__global__ __launch_bounds__(512, 8)
void k_main(const float4* __restrict__ xs, const float* __restrict__ x,
            const unsigned* __restrict__ perm,
            const unsigned* __restrict__ starts, const float2* __restrict__ tab,
            float4* __restrict__ out4)
{
    __shared__ float2 cache[CACHE_N];
    __shared__ int4 metaA[16];   // lo0, lo1, lo2, cbase
    __shared__ int4 metaB[16];   // n12, n2, bitcast(r), 0

    int cell = blockIdx.x;
    int startp = starts[cell], endp = starts[cell + 1];
    if (startp == endp) return;

    int ci = (cell >> 8) & 15, cj = (cell >> 4) & 15, ck = cell & 15;
    float fi0 = ci * 0.0625f, fi1 = (ci + 1) * 0.0625f;
    float fj0 = cj * 0.0625f, fj1 = (cj + 1) * 0.0625f;
    float fk0 = ck * 0.0625f, fk1 = (ck + 1) * 0.0625f;

    // -------- loader: all 512 threads, each unique corner gathered once ----
    int cbase = 0;
    #pragma unroll 1
    for (int l = 0; l < 16; ++l) {
        float r = c_res[l];
        int lo0 = (int)floorf(fi0 * r), hi0 = (int)ceilf(fi1 * r);
        int lo1 = (int)floorf(fj0 * r), hi1 = (int)ceilf(fj1 * r);
        int lo2 = (int)floorf(fk0 * r), hi2 = (int)ceilf(fk1 * r);
        int n0 = hi0 - lo0 + 1, n1 = hi1 - lo1 + 1, n2 = hi2 - lo2 + 1;
        int n12 = n1 * n2, tot = n0 * n12;
        for (int t = threadIdx.x; t < tot; t += 512) {
            int a = t / n12, rem = t - a * n12;
            int b = rem / n2, d = rem - b * n2;
            unsigned h = ((unsigned)(lo0 + a)
                        ^ ((unsigned)(lo1 + b) * PRIME1)
                        ^ ((unsigned)(lo2 + d) * PRIME2)) & TMASK;
            cache[cbase + t] = tab[h];
        }
        if (threadIdx.x == 0) {
            metaA[l] = make_int4(lo0, lo1, lo2, cbase);
            metaB[l] = make_int4(n12, n2, __float_as_int(r), 0);
        }
        cbase += tot;
    }
    __syncthreads();

    // -------- interp: all table reads from LDS, meta from LDS (uniform) ----
    auto lvl = [&](int l, float a0, float a1, float a2, float& ex, float& ey) {
        int4 mA = metaA[l];
        int4 mB = metaB[l];
        float r = __int_as_float(mB.z);
        int n12 = mB.x, n2 = mB.y;
        float s0 = a0 * r, s1 = a1 * r, s2 = a2 * r;   // lone mul == numpy
        float f0 = floorf(s0), f1 = floorf(s1), f2 = floorf(s2);
        float d0 = s0 - f0, d1 = s1 - f1, d2 = s2 - f2;
        int A0 = (int)f0 - mA.x, A1 = (int)f1 - mA.y, A2 = (int)f2 - mA.z;
        // ceil(s) = floor(s) + (s != floor(s)) for s >= 0
        int e0 = (d0 != 0.f) ? n12 : 0;
        int e1 = (d1 != 0.f) ? n2  : 0;
        int e2 = (d2 != 0.f) ? 1   : 0;
        int rA = mA.w + A0 * n12 + A1 * n2 + A2;

        float2 v0 = cache[rA];                 // 000
        float2 v1 = cache[rA + e0];            // 100
        float2 v2 = cache[rA + e1];            // 010
        float2 v3 = cache[rA + e2];            // 001
        float2 v4 = cache[rA + e0 + e1];       // 110
        float2 v5 = cache[rA + e0 + e2];       // 101
        float2 v6 = cache[rA + e1 + e2];       // 011
        float2 v7 = cache[rA + e0 + e1 + e2];  // 111

        float u0 = 1.f - d0, u1 = 1.f - d1, u2 = 1.f - d2;
        float pa = u1 * u2, pb = d1 * u2, pc = u1 * d2, pe = d1 * d2;
        float w0 = u0 * pa, w1 = d0 * pa, w2 = u0 * pb, w3 = u0 * pc;
        float w4 = d0 * pb, w5 = d0 * pc, w6 = u0 * pe, w7 = d0 * pe;

        float rx = v0.x * w0, ry = v0.y * w0;
        rx += v1.x * w1;  ry += v1.y * w1;
        rx += v2.x * w2;  ry += v2.y * w2;
        rx += v3.x * w3;  ry += v3.y * w3;
        rx += v4.x * w4;  ry += v4.y * w4;
        rx += v5.x * w5;  ry += v5.y * w5;
        rx += v6.x * w6;  ry += v6.y * w6;
        rx += v7.x * w7;  ry += v7.y * w7;
        ex = rx; ey = ry;
    };

    for (int sp = startp + (int)threadIdx.x; sp < endp; sp += 512) {
        float x0, x1, x2; unsigned p;
        if constexpr (MODE == 0) {
            float4 v = xs[sp];
            x0 = v.x; x1 = v.y; x2 = v.z; p = __float_as_uint(v.w);
        } else {
            p = perm[sp];
            x0 = x[3 * p]; x1 = x[3 * p + 1]; x2 = x[3 * p + 2];
        }
        // one thread writes the point's whole 128B output row, contiguously
        #pragma unroll 1
        for (int lp = 0; lp < 8; ++lp) {
            float4 o;
            lvl(2 * lp,     x0, x1, x2, o.x, o.y);
            lvl(2 * lp + 1, x0, x1, x2, o.z, o.w);
            out4[(size_t)p * 8 + lp] = o;
        }
    }
}

// Fallback (R1) if ws too small.
__global__ __launch_bounds__(256, 8)
void k_fallback(const float* __restrict__ x, const float2* __restrict__ tab,
                float2* __restrict__ out, int total) {
    int tid = blockIdx.x * 256 + threadIdx.x;
    if (tid >= total) return;
    int p = tid >> 4, l = tid & 15;
    float r = c_res[l];
    float s0 = x[3*p] * r, s1 = x[3*p+1] * r, s2 = x[3*p+2] * r;
    float f0 = floorf(s0), f1 = floorf(s1), f2 = floorf(s2);
    float d0 = s0 - f0, d1 = s1 - f1, d2 = s2 - f2;
    unsigned A0 = (unsigned)(int)f0, B0 = (unsigned)(int)ceilf(s0);
    unsigned A1 = (unsigned)(int)f1 * PRIME1, B1 = (unsigned)(int)ceilf(s1) * PRIME1;
    unsigned A2 = (unsigned)(int)f2 * PRIME2, B2 = (unsigned)(int)ceilf(s2) * PRIME2;
    unsigned h0=(A0^A1^A2)&TMASK, h1=(B0^A1^A2)&TMASK, h2=(A0^B1^A2)&TMASK;
    unsigned h3=(A0^A1^B2)&TMASK, h4=(B0^B1^A2)&TMASK, h5=(B0^A1^B2)&TMASK;
    unsigned h6=(A0^B1^B2)&TMASK, h7=(B0^B1^B2)&TMASK;
    float2 v0=tab[h0],v1=tab[h1],v2=tab[h2],v3=tab[h3];
    float2 v4=tab[h4],v5=tab[h5],v6=tab[h6],v7=tab[h7];
    float u0=1.f-d0,u1=1.f-d1,u2=1.f-d2;
    float ex = v0.x*(u0*u1*u2), ey = v0.y*(u0*u1*u2);
    ex += v1.x*(d0*u1*u2); ey += v1.y*(d0*u1*u2);
    ex += v2.x*(u0*d1*u2); ey += v2.y*(u0*d1*u2);
    ex += v3.x*(u0*u1*d2); ey += v3.y*(u0*u1*d2);
    ex += v4.x*(d0*d1*u2); ey += v4.y*(d0*d1*u2);
    ex += v5.x*(d0*u1*d2); ey += v5.y*(d0*u1*d2);
    ex += v6.x*(u0*d1*d2); ey += v6.y*(u0*d1*d2);
    ex += v7.x*(d0*d1*d2); ey += v7.y*(d0*d1*d2);
    float2 o; o.x = ex; o.y = ey; out[tid] = o;
}

extern "C" void kernel_launch(void* const* d_in, const int* in_sizes, int n_in,
                              void* d_out, int out_size, void* d_ws, size_t ws_size,
                              hipStream_t stream)
{
    const float*  x   = (const float*)d_in[0];
    const float2* tab = (const float2*)d_in[1];
    int npts = in_sizes[0] / 3;

    // common small arrays
    size_t off_hist   = 0;                                   // 16 KB
    size_t off_starts = off_hist + (size_t)NBUCKET * 4;      // 16 KB + 4
    size_t off_cursor = (off_starts + (size_t)(NBUCKET + 1) * 4 + 63) & ~(size_t)63;
    size_t off_pay    = (off_cursor + (size_t)NBUCKET * 4 + 63) & ~(size_t)63;

    // ---- Tier A: sorted-float4 payload (~16 MB ws) ----
    {
        size_t need = off_pay + (size_t)npts * 16;
        if (ws_size >= need) {
            unsigned* hist   = (unsigned*)((char*)d_ws + off_hist);
            unsigned* starts = (unsigned*)((char*)d_ws + off_starts);
            unsigned* cursor = (unsigned*)((char*)d_ws + off_cursor);
            float4*   xs     = (float4*)  ((char*)d_ws + off_pay);

            hipMemsetAsync(hist, 0, (size_t)NBUCKET * 4, stream);
            k_hist      <<<256, 256, 0, stream>>>(x, hist, npts);
            k_scan      <<<1, 1024, 0, stream>>>(hist, starts, cursor);
            k_scatter<0><<<2048, 256, 0, stream>>>(x, cursor, nullptr, xs, npts);
            k_main<0>   <<<NBUCKET, 512, 0, stream>>>(xs, x, nullptr, starts,
                                                      tab, (float4*)d_out);
            return;
        }
    }

    // ---- Tier B: perm-only payload (~4 MB ws) ----
    {
        size_t need = off_pay + (size_t)npts * 4;
        if (ws_size >= need) {
            unsigned* hist   = (unsigned*)((char*)d_ws + off_hist);
            unsigned* starts = (unsigned*)((char*)d_ws + off_starts);
            unsigned* cursor = (unsigned*)((char*)d_ws + off_cursor);
            unsigned* perm   = (unsigned*)((char*)d_ws + off_pay);

            hipMemsetAsync(hist, 0, (size_t)NBUCKET * 4, stream);
            k_hist      <<<256, 256, 0, stream>>>(x, hist, npts);
            k_scan      <<<1, 1024, 0, stream>>>(hist, starts, cursor);
            k_scatter<1><<<2048, 256, 0, stream>>>(x, cursor, perm, nullptr, npts);
            k_main<1>   <<<NBUCKET, 512, 0, stream>>>(nullptr, x, perm, starts,
                                                      tab, (float4*)d_out);
            return;
        }
    }

    // ---- fallback ----
    int total = npts * 16;
    k_fallback<<<(total + 255) / 256, 256, 0, stream>>>(
        x, tab, (float2*)d_out, total);
}

// Round 4
// 278.676 us; speedup vs baseline: 2.1957x; 1.1161x over previous
//
#include <hip/hip_runtime.h>

// Instant-NGP multires hash encoding fwd. N=1M, L=16, F=2, T=2^19.
// R8 (from R7 @ 311us; best prior R5 @ 258us):
//  - aux: back to R5's atomic-free matrix sort (cnt/colscan/LDS-cursor scatter;
//    R7's global-atomic cursors serialized at L2 and regressed). k_hist and
//    k_scatter get 1024-thread blocks (were 256): they were latency-bound at
//    4 waves/CU; traffic is only ~56MB total.
//  - k_main: R7's 512-thread single-pass kernel (107us, 32 waves/CU) plus:
//    paired z-neighbor LDS loads — always read cache[idx] and cache[idx+1]
//    (LLVM merges to ds_read2_b64), select by (d2!=0) cndmask. 8 -> 4 LDS
//    issue slots per level. Cache padded +1 so +1 is always in-bounds.
//  - Per-point 128B output row still written once, contiguously (R6 lesson:
//    splitting it across passes tripled HBM writes).

__constant__ float c_res[16] = {
    16.f, 18.f, 21.f, 24.f, 27.f, 32.f, 36.f, 42.f,
    48.f, 55.f, 64.f, 73.f, 84.f, 97.f, 111.f, 128.f
};

#define TMASK   0x7FFFFu
#define PRIME1  2654435761u
#define PRIME2  805459861u
#define NBUCKET 4096          // 16^3 cells
#define NB      256           // sort blocks
#define CACHE_N 4467          // sum over levels of max corners — exact bound

__device__ __forceinline__ int bucket_of(float x0, float x1, float x2) {
    // x*16 is EXACT in fp32 (power-of-2 scale), so cell membership is exact.
    int c0 = (int)(x0 * 16.f); c0 = c0 < 0 ? 0 : (c0 > 15 ? 15 : c0);
    int c1 = (int)(x1 * 16.f); c1 = c1 < 0 ? 0 : (c1 > 15 ? 15 : c1);
    int c2 = (int)(x2 * 16.f); c2 = c2 < 0 ? 0 : (c2 > 15 ? 15 : c2);
    return (c0 << 8) | (c1 << 4) | c2;
}

// ---- sort: per-block LDS histogram, no global atomics anywhere ----

__global__ __launch_bounds__(1024)
void k_hist(const float* __restrict__ x, unsigned* __restrict__ cnt, int npts) {
    __shared__ unsigned h[NBUCKET];
    for (int i = threadIdx.x; i < NBUCKET; i += 1024) h[i] = 0u;
    __syncthreads();
    int chunk = (npts + NB - 1) / NB;
    int begin = blockIdx.x * chunk;
    int end   = begin + chunk; if (end > npts) end = npts;
    for (int i = begin + threadIdx.x; i < end; i += 1024) {
        int b = bucket_of(x[3 * i], x[3 * i + 1], x[3 * i + 2]);
        atomicAdd(&h[b], 1u);          // LDS atomic — cheap
    }
    __syncthreads();
    for (int i = threadIdx.x; i < NBUCKET; i += 1024)
        cnt[blockIdx.x * NBUCKET + i] = h[i];
}

// base[b][j] = sum over blocks<b of cnt[.][j]; colsum[j] = column total.
// 128 blocks x 256 threads: 32 columns/block, 8 row-groups/column.
__global__ __launch_bounds__(256)
void k_colscan(const unsigned* __restrict__ cnt, unsigned* __restrict__ base,
               unsigned* __restrict__ colsum) {
    const int RPG = NB / 8;
    int col = blockIdx.x * 32 + (threadIdx.x & 31);
    int rg  = threadIdx.x >> 5;
    unsigned loc[RPG];
    unsigned s = 0;
    #pragma unroll
    for (int r = 0; r < RPG; ++r) {
        unsigned v = cnt[(size_t)(rg * RPG + r) * NBUCKET + col];
        loc[r] = s;                     // exclusive within row-group
        s += v;
    }
    __shared__ unsigned t[8][32];
    t[rg][threadIdx.x & 31] = s;
    __syncthreads();
    unsigned pre = 0;
    for (int g = 0; g < rg; ++g) pre += t[g][threadIdx.x & 31];
    #pragma unroll
    for (int r = 0; r < RPG; ++r)
        base[(size_t)(rg * RPG + r) * NBUCKET + col] = pre + loc[r];
    if (rg == 7) colsum[col] = pre + s;
}

// One block: exclusive scan of colsum[4096] -> starts[0..4096].
__global__ __launch_bounds__(1024)
void k_scan(const unsigned* __restrict__ colsum, unsigned* __restrict__ starts) {
    __shared__ unsigned tmp[1024];
    int t = threadIdx.x;
    unsigned v0 = colsum[4 * t + 0], v1 = colsum[4 * t + 1];
    unsigned v2 = colsum[4 * t + 2], v3 = colsum[4 * t + 3];
    unsigned s = v0 + v1 + v2 + v3;
    tmp[t] = s;
    __syncthreads();
    for (int off = 1; off < 1024; off <<= 1) {
        unsigned u = (t >= off) ? tmp[t - off] : 0u;
        __syncthreads();
        tmp[t] += u;
        __syncthreads();
    }
    unsigned excl = tmp[t] - s;
    starts[4 * t + 0] = excl;
    starts[4 * t + 1] = excl + v0;
    starts[4 * t + 2] = excl + v0 + v1;
    starts[4 * t + 3] = excl + v0 + v1 + v2;
    if (t == 1023) starts[4096] = tmp[1023];
}

// MODE 0: write sorted float4{x,y,z,bitcast(i)}.  MODE 1: write perm only.
template<int MODE>
__global__ __launch_bounds__(1024)
void k_scatter(const float* __restrict__ x, const unsigned* __restrict__ base,
               const unsigned* __restrict__ starts, unsigned* __restrict__ perm,
               float4* __restrict__ xs, int npts) {
    __shared__ unsigned cur[NBUCKET];
    for (int i = threadIdx.x; i < NBUCKET; i += 1024)
        cur[i] = starts[i] + base[blockIdx.x * NBUCKET + i];
    __syncthreads();
    int chunk = (npts + NB - 1) / NB;
    int begin = blockIdx.x * chunk;
    int end   = begin + chunk; if (end > npts) end = npts;
    for (int i = begin + threadIdx.x; i < end; i += 1024) {
        float x0 = x[3 * i], x1 = x[3 * i + 1], x2 = x[3 * i + 2];
        int b = bucket_of(x0, x1, x2);
        unsigned pos = atomicAdd(&cur[b], 1u);   // LDS atomic
        if constexpr (MODE == 0) {
            float4 v; v.x = x0; v.y = x1; v.z = x2;
            v.w = __uint_as_float((unsigned)i);
            xs[pos] = v;
        } else {
            perm[pos] = (unsigned)i;
        }
    }
}

// ---- main: per-cell LDS corner cache, single pass over all 16 levels ----
// Box per level for cell i: lo=floor((i/16)*r), hi=ceil(((i+1)/16)*r).
// i*r<=2048 is fp32-exact, /16 dyadic-exact => bounds exact; fp-mul
// monotonicity => every per-point floor/ceil coord lies in [lo,hi].

template<int MODE>   // 0: sorted xs.  1: perm + scattered x
__global__ __launch_bounds__(512, 8)
void k_main(const float4* __restrict__ xs, const float* __restrict__ x,
            const unsigned* __restrict__ perm,
            const unsigned* __restrict__ starts, const float2* __restrict__ tab,
            float4* __restrict__ out4)
{
    __shared__ float2 cache[CACHE_N + 1];   // +1: z-pair loads may touch +1
    __shared__ int4 metaA[16];   // lo0, lo1, lo2, cbase
    __shared__ int4 metaB[16];   // n12, n2, bitcast(r), 0

    int cell = blockIdx.x;
    int startp = starts[cell], endp = starts[cell + 1];
    if (startp == endp) return;

    int ci = (cell >> 8) & 15, cj = (cell >> 4) & 15, ck = cell & 15;
    float fi0 = ci * 0.0625f, fi1 = (ci + 1) * 0.0625f;
    float fj0 = cj * 0.0625f, fj1 = (cj + 1) * 0.0625f;
    float fk0 = ck * 0.0625f, fk1 = (ck + 1) * 0.0625f;

    // -------- loader: all 512 threads, each unique corner gathered once ----
    int cbase = 0;
    #pragma unroll 1
    for (int l = 0; l < 16; ++l) {
        float r = c_res[l];
        int lo0 = (int)floorf(fi0 * r), hi0 = (int)ceilf(fi1 * r);
        int lo1 = (int)floorf(fj0 * r), hi1 = (int)ceilf(fj1 * r);
        int lo2 = (int)floorf(fk0 * r), hi2 = (int)ceilf(fk1 * r);
        int n0 = hi0 - lo0 + 1, n1 = hi1 - lo1 + 1, n2 = hi2 - lo2 + 1;
        int n12 = n1 * n2, tot = n0 * n12;
        for (int t = threadIdx.x; t < tot; t += 512) {
            int a = t / n12, rem = t - a * n12;
            int b = rem / n2, d = rem - b * n2;
            unsigned h = ((unsigned)(lo0 + a)
                        ^ ((unsigned)(lo1 + b) * PRIME1)
                        ^ ((unsigned)(lo2 + d) * PRIME2)) & TMASK;
            cache[cbase + t] = tab[h];
        }
        if (threadIdx.x == 0) {
            metaA[l] = make_int4(lo0, lo1, lo2, cbase);
            metaB[l] = make_int4(n12, n2, __float_as_int(r), 0);
        }
        cbase += tot;
    }
    __syncthreads();

    // -------- interp: all table reads from LDS, meta from LDS (uniform) ----
    auto lvl = [&](int l, float a0, float a1, float a2, float& ex, float& ey) {
        int4 mA = metaA[l];
        int4 mB = metaB[l];
        float r = __int_as_float(mB.z);
        int n12 = mB.x, n2 = mB.y;
        float s0 = a0 * r, s1 = a1 * r, s2 = a2 * r;   // lone mul == numpy
        float f0 = floorf(s0), f1 = floorf(s1), f2 = floorf(s2);
        float d0 = s0 - f0, d1 = s1 - f1, d2 = s2 - f2;
        int A0 = (int)f0 - mA.x, A1 = (int)f1 - mA.y, A2 = (int)f2 - mA.z;
        // ceil(s) = floor(s) + (s != floor(s)) for s >= 0
        int e0 = (d0 != 0.f) ? n12 : 0;
        int e1 = (d1 != 0.f) ? n2  : 0;
        bool e2 = (d2 != 0.f);
        int rA = mA.w + A0 * n12 + A1 * n2 + A2;
        int rB = rA + e1, rC = rA + e0, rD = rA + e0 + e1;

        // paired z-loads: [idx], [idx+1] merge to ds_read2_b64; select by e2.
        // When e2==0 the +1 value is discarded (in-bounds via +1 pad).
        float2 pa0 = cache[rA], pa1 = cache[rA + 1];
        float2 pb0 = cache[rB], pb1 = cache[rB + 1];
        float2 pc0 = cache[rC], pc1 = cache[rC + 1];
        float2 pd0 = cache[rD], pd1 = cache[rD + 1];
        float2 v0 = pa0;                 // 000
        float2 v3 = e2 ? pa1 : pa0;      // 001
        float2 v2 = pb0;                 // 010
        float2 v6 = e2 ? pb1 : pb0;      // 011
        float2 v1 = pc0;                 // 100
        float2 v5 = e2 ? pc1 : pc0;      // 101
        float2 v4 = pd0;                 // 110
        float2 v7 = e2 ? pd1 : pd0;      // 111

        float u0 = 1.f - d0, u1 = 1.f - d1, u2 = 1.f - d2;
        float pa = u1 * u2, pb = d1 * u2, pc = u1 * d2, pe = d1 * d2;
        float w0 = u0 * pa, w1 = d0 * pa, w2 = u0 * pb, w3 = u0 * pc;
        float w4 = d0 * pb, w5 = d0 * pc, w6 = u0 * pe, w7 = d0 * pe;

        float rx = v0.x * w0, ry = v0.y * w0;
        rx += v1.x * w1;  ry += v1.y * w1;
        rx += v2.x * w2;  ry += v2.y * w2;
        rx += v3.x * w3;  ry += v3.y * w3;
        rx += v4.x * w4;  ry += v4.y * w4;
        rx += v5.x * w5;  ry += v5.y * w5;
        rx += v6.x * w6;  ry += v6.y * w6;
        rx += v7.x * w7;  ry += v7.y * w7;
        ex = rx; ey = ry;
    };

    for (int sp = startp + (int)threadIdx.x; sp < endp; sp += 512) {
        float x0, x1, x2; unsigned p;
        if constexpr (MODE == 0) {
            float4 v = xs[sp];
            x0 = v.x; x1 = v.y; x2 = v.z; p = __float_as_uint(v.w);
        } else {
            p = perm[sp];
            x0 = x[3 * p]; x1 = x[3 * p + 1]; x2 = x[3 * p + 2];
        }
        // one thread writes the point's whole 128B output row, contiguously
        #pragma unroll 1
        for (int lp = 0; lp < 8; ++lp) {
            float4 o;
            lvl(2 * lp,     x0, x1, x2, o.x, o.y);
            lvl(2 * lp + 1, x0, x1, x2, o.z, o.w);
            out4[(size_t)p * 8 + lp] = o;
        }
    }
}

// Fallback (R1) if ws too small.
__global__ __launch_bounds__(256, 8)
void k_fallback(const float* __restrict__ x, const float2* __restrict__ tab,
                float2* __restrict__ out, int total) {
    int tid = blockIdx.x * 256 + threadIdx.x;
    if (tid >= total) return;
    int p = tid >> 4, l = tid & 15;
    float r = c_res[l];
    float s0 = x[3*p] * r, s1 = x[3*p+1] * r, s2 = x[3*p+2] * r;
    float f0 = floorf(s0), f1 = floorf(s1), f2 = floorf(s2);
    float d0 = s0 - f0, d1 = s1 - f1, d2 = s2 - f2;
    unsigned A0 = (unsigned)(int)f0, B0 = (unsigned)(int)ceilf(s0);
    unsigned A1 = (unsigned)(int)f1 * PRIME1, B1 = (unsigned)(int)ceilf(s1) * PRIME1;
    unsigned A2 = (unsigned)(int)f2 * PRIME2, B2 = (unsigned)(int)ceilf(s2) * PRIME2;
    unsigned h0=(A0^A1^A2)&TMASK, h1=(B0^A1^A2)&TMASK, h2=(A0^B1^A2)&TMASK;
    unsigned h3=(A0^A1^B2)&TMASK, h4=(B0^B1^A2)&TMASK, h5=(B0^A1^B2)&TMASK;
    unsigned h6=(A0^B1^B2)&TMASK, h7=(B0^B1^B2)&TMASK;
    float2 v0=tab[h0],v1=tab[h1],v2=tab[h2],v3=tab[h3];
    float2 v4=tab[h4],v5=tab[h5],v6=tab[h6],v7=tab[h7];
    float u0=1.f-d0,u1=1.f-d1,u2=1.f-d2;
    float ex = v0.x*(u0*u1*u2), ey = v0.y*(u0*u1*u2);
    ex += v1.x*(d0*u1*u2); ey += v1.y*(d0*u1*u2);
    ex += v2.x*(u0*d1*u2); ey += v2.y*(u0*d1*u2);
    ex += v3.x*(u0*u1*d2); ey += v3.y*(u0*u1*d2);
    ex += v4.x*(d0*d1*u2); ey += v4.y*(d0*d1*u2);
    ex += v5.x*(d0*u1*d2); ey += v5.y*(d0*u1*d2);
    ex += v6.x*(u0*d1*d2); ey += v6.y*(u0*d1*d2);
    ex += v7.x*(d0*d1*d2); ey += v7.y*(d0*d1*d2);
    float2 o; o.x = ex; o.y = ey; out[tid] = o;
}

extern "C" void kernel_launch(void* const* d_in, const int* in_sizes, int n_in,
                              void* d_out, int out_size, void* d_ws, size_t ws_size,
                              hipStream_t stream)
{
    const float*  x   = (const float*)d_in[0];
    const float2* tab = (const float2*)d_in[1];
    int npts = in_sizes[0] / 3;

    // ws layout (shared head)
    size_t off_cnt    = 0;                                        // 4 MB
    size_t off_base   = off_cnt    + (size_t)NB * NBUCKET * 4;    // 4 MB
    size_t off_colsum = off_base   + (size_t)NB * NBUCKET * 4;    // 16 KB
    size_t off_starts = off_colsum + (size_t)NBUCKET * 4;
    size_t off_pay    = (off_starts + (size_t)(NBUCKET + 1) * 4 + 63)
                        & ~(size_t)63;

    // ---- Tier A: sorted-float4 payload (~24 MB ws) ----
    {
        size_t need = off_pay + (size_t)npts * 16;
        if (ws_size >= need) {
            unsigned* cnt    = (unsigned*)((char*)d_ws + off_cnt);
            unsigned* base   = (unsigned*)((char*)d_ws + off_base);
            unsigned* colsum = (unsigned*)((char*)d_ws + off_colsum);
            unsigned* starts = (unsigned*)((char*)d_ws + off_starts);
            float4*   xs     = (float4*)  ((char*)d_ws + off_pay);

            k_hist      <<<NB, 1024, 0, stream>>>(x, cnt, npts);
            k_colscan   <<<NBUCKET / 32, 256, 0, stream>>>(cnt, base, colsum);
            k_scan      <<<1, 1024, 0, stream>>>(colsum, starts);
            k_scatter<0><<<NB, 1024, 0, stream>>>(x, base, starts,
                                                  nullptr, xs, npts);
            k_main<0>   <<<NBUCKET, 512, 0, stream>>>(xs, x, nullptr, starts,
                                                      tab, (float4*)d_out);
            return;
        }
    }

    // ---- Tier B: perm-only payload (~12 MB ws) ----
    {
        size_t need = off_pay + (size_t)npts * 4;
        if (ws_size >= need) {
            unsigned* cnt    = (unsigned*)((char*)d_ws + off_cnt);
            unsigned* base   = (unsigned*)((char*)d_ws + off_base);
            unsigned* colsum = (unsigned*)((char*)d_ws + off_colsum);
            unsigned* starts = (unsigned*)((char*)d_ws + off_starts);
            unsigned* perm   = (unsigned*)((char*)d_ws + off_pay);

            k_hist      <<<NB, 1024, 0, stream>>>(x, cnt, npts);
            k_colscan   <<<NBUCKET / 32, 256, 0, stream>>>(cnt, base, colsum);
            k_scan      <<<1, 1024, 0, stream>>>(colsum, starts);
            k_scatter<1><<<NB, 1024, 0, stream>>>(x, base, starts,
                                                  perm, nullptr, npts);
            k_main<1>   <<<NBUCKET, 512, 0, stream>>>(nullptr, x, perm, starts,
                                                      tab, (float4*)d_out);
            return;
        }
    }

    // ---- fallback ----
    int total = npts * 16;
    k_fallback<<<(total + 255) / 256, 256, 0, stream>>>(
        x, tab, (float2*)d_out, total);
}

// Round 5
// 247.595 us; speedup vs baseline: 2.4714x; 1.1255x over previous
//
#include <hip/hip_runtime.h>

// Instant-NGP multires hash encoding fwd. N=1M, L=16, F=2, T=2^19.
// R9 (from R8 @ 278us; k_main reverted to R7's proven 107us form):
//  - k_main: R7 interp exactly — 8 direct ds_read_b64 per level (R8's paired
//    z-loads DOUBLED bank conflicts 4.5M->9.8M and regressed 107->138).
//  - aux: 5 dispatches -> 3 (memset + 2 kernels). k_histA writes cnt row and
//    atomic-merges into grpsum[blk/16] (16-way contention, overlapped).
//    k_scatB rebuilds all prefix info itself from L2-resident grpsum/cnt rows
//    (<=31 uint4 loads/thread) + replicated 4096-wide LDS scan, then scatters.
//    colscan/scan kernels and their serialization gaps are gone.

__constant__ float c_res[16] = {
    16.f, 18.f, 21.f, 24.f, 27.f, 32.f, 36.f, 42.f,
    48.f, 55.f, 64.f, 73.f, 84.f, 97.f, 111.f, 128.f
};

#define TMASK   0x7FFFFu
#define PRIME1  2654435761u
#define PRIME2  805459861u
#define NBUCKET 4096          // 16^3 cells
#define NB      256           // sort blocks (hist & scatter use SAME chunking)
#define NGRP    16            // grpsum rows; group = 16 consecutive blocks
#define CACHE_N 4467          // sum over levels of max corners — exact bound

__device__ __forceinline__ int bucket_of(float x0, float x1, float x2) {
    // x*16 is EXACT in fp32 (power-of-2 scale), so cell membership is exact.
    int c0 = (int)(x0 * 16.f); c0 = c0 < 0 ? 0 : (c0 > 15 ? 15 : c0);
    int c1 = (int)(x1 * 16.f); c1 = c1 < 0 ? 0 : (c1 > 15 ? 15 : c1);
    int c2 = (int)(x2 * 16.f); c2 = c2 < 0 ? 0 : (c2 > 15 ? 15 : c2);
    return (c0 << 8) | (c1 << 4) | c2;
}

// ---- aux 1: per-block LDS histogram -> cnt row + grpsum atomic merge ----
__global__ __launch_bounds__(1024)
void k_histA(const float* __restrict__ x, unsigned* __restrict__ cnt,
             unsigned* __restrict__ grpsum, int npts)
{
    __shared__ unsigned h[NBUCKET];
    for (int j = threadIdx.x; j < NBUCKET; j += 1024) h[j] = 0u;
    __syncthreads();
    int chunk = (npts + NB - 1) / NB;
    int begin = blockIdx.x * chunk;
    int end   = begin + chunk; if (end > npts) end = npts;
    for (int i = begin + threadIdx.x; i < end; i += 1024) {
        int b = bucket_of(x[3 * i], x[3 * i + 1], x[3 * i + 2]);
        atomicAdd(&h[b], 1u);              // LDS atomic — cheap
    }
    __syncthreads();
    unsigned* grow = grpsum + (size_t)(blockIdx.x >> 4) * NBUCKET;
    for (int j = threadIdx.x; j < NBUCKET; j += 1024) {
        unsigned v = h[j];
        cnt[(size_t)blockIdx.x * NBUCKET + j] = v;
        if (v) atomicAdd(&grow[j], v);     // ~700K atomics, 16-way avg
    }
}

// ---- aux 2: rebuild prefix info per block, then scatter ----
// cursor(blk, j) = starts[j] + sum_{g < blk/16} grpsum[g][j]
//                + sum_{r in [blk&~15, blk)} cnt[r][j]
// starts[] = exclusive scan over colsum = sum_g grpsum[g].
template<int MODE>   // 0: float4{x,y,z,bitcast(i)}  1: perm only
__global__ __launch_bounds__(1024)
void k_scatB(const float* __restrict__ x, const unsigned* __restrict__ cnt,
             const unsigned* __restrict__ grpsum, unsigned* __restrict__ starts,
             unsigned* __restrict__ perm, float4* __restrict__ xs, int npts)
{
    __shared__ unsigned cur[NBUCKET];
    __shared__ unsigned tmp[1024];
    const int t   = threadIdx.x;
    const int blk = blockIdx.x;
    const int myg = blk >> 4;
    const int r0  = blk & ~15;

    const uint4* gs4 = (const uint4*)grpsum;   // [NGRP][1024] uint4
    const uint4* ct4 = (const uint4*)cnt;      // [NB]  [1024] uint4
    uint4 tot = make_uint4(0u,0u,0u,0u), bas = make_uint4(0u,0u,0u,0u);
    #pragma unroll
    for (int g = 0; g < NGRP; ++g) {
        uint4 v = gs4[g * 1024 + t];
        tot.x += v.x; tot.y += v.y; tot.z += v.z; tot.w += v.w;
        if (g < myg) { bas.x += v.x; bas.y += v.y; bas.z += v.z; bas.w += v.w; }
    }
    for (int r = r0; r < blk; ++r) {
        uint4 v = ct4[r * 1024 + t];
        bas.x += v.x; bas.y += v.y; bas.z += v.z; bas.w += v.w;
    }
    // replicated exclusive scan of the 4096 column totals
    unsigned s = tot.x + tot.y + tot.z + tot.w;
    tmp[t] = s;
    __syncthreads();
    for (int off = 1; off < 1024; off <<= 1) {
        unsigned u = (t >= off) ? tmp[t - off] : 0u;
        __syncthreads();
        tmp[t] += u;
        __syncthreads();
    }
    unsigned excl = tmp[t] - s;
    unsigned s0 = excl, s1 = s0 + tot.x, s2 = s1 + tot.y, s3 = s2 + tot.z;
    cur[4*t+0] = s0 + bas.x;
    cur[4*t+1] = s1 + bas.y;
    cur[4*t+2] = s2 + bas.z;
    cur[4*t+3] = s3 + bas.w;
    if (blk == 0) {        // publish starts for k_main
        starts[4*t+0] = s0; starts[4*t+1] = s1;
        starts[4*t+2] = s2; starts[4*t+3] = s3;
        if (t == 1023) starts[NBUCKET] = tmp[1023];
    }
    __syncthreads();

    int chunk = (npts + NB - 1) / NB;     // SAME chunking as k_histA
    int begin = blk * chunk;
    int end   = begin + chunk; if (end > npts) end = npts;
    for (int i = begin + t; i < end; i += 1024) {
        float x0 = x[3 * i], x1 = x[3 * i + 1], x2 = x[3 * i + 2];
        int b = bucket_of(x0, x1, x2);
        unsigned pos = atomicAdd(&cur[b], 1u);   // LDS atomic
        if constexpr (MODE == 0) {
            float4 v; v.x = x0; v.y = x1; v.z = x2;
            v.w = __uint_as_float((unsigned)i);
            xs[pos] = v;
        } else {
            perm[pos] = (unsigned)i;
        }
    }
}

// ---- main: per-cell LDS corner cache, single pass over all 16 levels ----
// Box per level for cell i: lo=floor((i/16)*r), hi=ceil(((i+1)/16)*r).
// i*r<=2048 is fp32-exact, /16 dyadic-exact => bounds exact; fp-mul
// monotonicity => every per-point floor/ceil coord lies in [lo,hi].
// (R7 form, verbatim: 107us, VALUBusy 78%, 4.5M bank conflicts.)

template<int MODE>   // 0: sorted xs.  1: perm + scattered x
__global__ __launch_bounds__(512, 8)
void k_main(const float4* __restrict__ xs, const float* __restrict__ x,
            const unsigned* __restrict__ perm,
            const unsigned* __restrict__ starts, const float2* __restrict__ tab,
            float4* __restrict__ out4)
{
    __shared__ float2 cache[CACHE_N];
    __shared__ int4 metaA[16];   // lo0, lo1, lo2, cbase
    __shared__ int4 metaB[16];   // n12, n2, bitcast(r), 0

    int cell = blockIdx.x;
    int startp = starts[cell], endp = starts[cell + 1];
    if (startp == endp) return;

    int ci = (cell >> 8) & 15, cj = (cell >> 4) & 15, ck = cell & 15;
    float fi0 = ci * 0.0625f, fi1 = (ci + 1) * 0.0625f;
    float fj0 = cj * 0.0625f, fj1 = (cj + 1) * 0.0625f;
    float fk0 = ck * 0.0625f, fk1 = (ck + 1) * 0.0625f;

    // -------- loader: all 512 threads, each unique corner gathered once ----
    int cbase = 0;
    #pragma unroll 1
    for (int l = 0; l < 16; ++l) {
        float r = c_res[l];
        int lo0 = (int)floorf(fi0 * r), hi0 = (int)ceilf(fi1 * r);
        int lo1 = (int)floorf(fj0 * r), hi1 = (int)ceilf(fj1 * r);
        int lo2 = (int)floorf(fk0 * r), hi2 = (int)ceilf(fk1 * r);
        int n0 = hi0 - lo0 + 1, n1 = hi1 - lo1 + 1, n2 = hi2 - lo2 + 1;
        int n12 = n1 * n2, tot = n0 * n12;
        for (int t = threadIdx.x; t < tot; t += 512) {
            int a = t / n12, rem = t - a * n12;
            int b = rem / n2, d = rem - b * n2;
            unsigned h = ((unsigned)(lo0 + a)
                        ^ ((unsigned)(lo1 + b) * PRIME1)
                        ^ ((unsigned)(lo2 + d) * PRIME2)) & TMASK;
            cache[cbase + t] = tab[h];
        }
        if (threadIdx.x == 0) {
            metaA[l] = make_int4(lo0, lo1, lo2, cbase);
            metaB[l] = make_int4(n12, n2, __float_as_int(r), 0);
        }
        cbase += tot;
    }
    __syncthreads();

    // -------- interp: all table reads from LDS, meta from LDS (uniform) ----
    auto lvl = [&](int l, float a0, float a1, float a2, float& ex, float& ey) {
        int4 mA = metaA[l];
        int4 mB = metaB[l];
        float r = __int_as_float(mB.z);
        int n12 = mB.x, n2 = mB.y;
        float s0 = a0 * r, s1 = a1 * r, s2 = a2 * r;   // lone mul == numpy
        float f0 = floorf(s0), f1 = floorf(s1), f2 = floorf(s2);
        float d0 = s0 - f0, d1 = s1 - f1, d2 = s2 - f2;
        int A0 = (int)f0 - mA.x, A1 = (int)f1 - mA.y, A2 = (int)f2 - mA.z;
        // ceil(s) = floor(s) + (s != floor(s)) for s >= 0
        int e0 = (d0 != 0.f) ? n12 : 0;
        int e1 = (d1 != 0.f) ? n2  : 0;
        int e2 = (d2 != 0.f) ? 1   : 0;
        int rA = mA.w + A0 * n12 + A1 * n2 + A2;

        float2 v0 = cache[rA];                 // 000
        float2 v1 = cache[rA + e0];            // 100
        float2 v2 = cache[rA + e1];            // 010
        float2 v3 = cache[rA + e2];            // 001
        float2 v4 = cache[rA + e0 + e1];       // 110
        float2 v5 = cache[rA + e0 + e2];       // 101
        float2 v6 = cache[rA + e1 + e2];       // 011
        float2 v7 = cache[rA + e0 + e1 + e2];  // 111

        float u0 = 1.f - d0, u1 = 1.f - d1, u2 = 1.f - d2;
        float pa = u1 * u2, pb = d1 * u2, pc = u1 * d2, pe = d1 * d2;
        float w0 = u0 * pa, w1 = d0 * pa, w2 = u0 * pb, w3 = u0 * pc;
        float w4 = d0 * pb, w5 = d0 * pc, w6 = u0 * pe, w7 = d0 * pe;

        float rx = v0.x * w0, ry = v0.y * w0;
        rx += v1.x * w1;  ry += v1.y * w1;
        rx += v2.x * w2;  ry += v2.y * w2;
        rx += v3.x * w3;  ry += v3.y * w3;
        rx += v4.x * w4;  ry += v4.y * w4;
        rx += v5.x * w5;  ry += v5.y * w5;
        rx += v6.x * w6;  ry += v6.y * w6;
        rx += v7.x * w7;  ry += v7.y * w7;
        ex = rx; ey = ry;
    };

    for (int sp = startp + (int)threadIdx.x; sp < endp; sp += 512) {
        float x0, x1, x2; unsigned p;
        if constexpr (MODE == 0) {
            float4 v = xs[sp];
            x0 = v.x; x1 = v.y; x2 = v.z; p = __float_as_uint(v.w);
        } else {
            p = perm[sp];
            x0 = x[3 * p]; x1 = x[3 * p + 1]; x2 = x[3 * p + 2];
        }
        // one thread writes the point's whole 128B output row, contiguously
        #pragma unroll 1
        for (int lp = 0; lp < 8; ++lp) {
            float4 o;
            lvl(2 * lp,     x0, x1, x2, o.x, o.y);
            lvl(2 * lp + 1, x0, x1, x2, o.z, o.w);
            out4[(size_t)p * 8 + lp] = o;
        }
    }
}

// Fallback (R1) if ws too small.
__global__ __launch_bounds__(256, 8)
void k_fallback(const float* __restrict__ x, const float2* __restrict__ tab,
                float2* __restrict__ out, int total) {
    int tid = blockIdx.x * 256 + threadIdx.x;
    if (tid >= total) return;
    int p = tid >> 4, l = tid & 15;
    float r = c_res[l];
    float s0 = x[3*p] * r, s1 = x[3*p+1] * r, s2 = x[3*p+2] * r;
    float f0 = floorf(s0), f1 = floorf(s1), f2 = floorf(s2);
    float d0 = s0 - f0, d1 = s1 - f1, d2 = s2 - f2;
    unsigned A0 = (unsigned)(int)f0, B0 = (unsigned)(int)ceilf(s0);
    unsigned A1 = (unsigned)(int)f1 * PRIME1, B1 = (unsigned)(int)ceilf(s1) * PRIME1;
    unsigned A2 = (unsigned)(int)f2 * PRIME2, B2 = (unsigned)(int)ceilf(s2) * PRIME2;
    unsigned h0=(A0^A1^A2)&TMASK, h1=(B0^A1^A2)&TMASK, h2=(A0^B1^A2)&TMASK;
    unsigned h3=(A0^A1^B2)&TMASK, h4=(B0^B1^A2)&TMASK, h5=(B0^A1^B2)&TMASK;
    unsigned h6=(A0^B1^B2)&TMASK, h7=(B0^B1^B2)&TMASK;
    float2 v0=tab[h0],v1=tab[h1],v2=tab[h2],v3=tab[h3];
    float2 v4=tab[h4],v5=tab[h5],v6=tab[h6],v7=tab[h7];
    float u0=1.f-d0,u1=1.f-d1,u2=1.f-d2;
    float ex = v0.x*(u0*u1*u2), ey = v0.y*(u0*u1*u2);
    ex += v1.x*(d0*u1*u2); ey += v1.y*(d0*u1*u2);
    ex += v2.x*(u0*d1*u2); ey += v2.y*(u0*d1*u2);
    ex += v3.x*(u0*u1*d2); ey += v3.y*(u0*u1*d2);
    ex += v4.x*(d0*d1*u2); ey += v4.y*(d0*d1*u2);
    ex += v5.x*(d0*u1*d2); ey += v5.y*(d0*u1*d2);
    ex += v6.x*(u0*d1*d2); ey += v6.y*(u0*d1*d2);
    ex += v7.x*(d0*d1*d2); ey += v7.y*(d0*d1*d2);
    float2 o; o.x = ex; o.y = ey; out[tid] = o;
}

extern "C" void kernel_launch(void* const* d_in, const int* in_sizes, int n_in,
                              void* d_out, int out_size, void* d_ws, size_t ws_size,
                              hipStream_t stream)
{
    const float*  x   = (const float*)d_in[0];
    const float2* tab = (const float2*)d_in[1];
    int npts = in_sizes[0] / 3;

    // ws layout (shared head)
    size_t off_grpsum = 0;                                        // 256 KB
    size_t off_cnt    = off_grpsum + (size_t)NGRP * NBUCKET * 4;  // 4 MB
    size_t off_starts = off_cnt    + (size_t)NB * NBUCKET * 4;
    size_t off_pay    = (off_starts + (size_t)(NBUCKET + 1) * 4 + 63)
                        & ~(size_t)63;

    // ---- Tier A: sorted-float4 payload (~20.5 MB ws) ----
    {
        size_t need = off_pay + (size_t)npts * 16;
        if (ws_size >= need) {
            unsigned* grpsum = (unsigned*)((char*)d_ws + off_grpsum);
            unsigned* cnt    = (unsigned*)((char*)d_ws + off_cnt);
            unsigned* starts = (unsigned*)((char*)d_ws + off_starts);
            float4*   xs     = (float4*)  ((char*)d_ws + off_pay);

            hipMemsetAsync(grpsum, 0, (size_t)NGRP * NBUCKET * 4, stream);
            k_histA     <<<NB, 1024, 0, stream>>>(x, cnt, grpsum, npts);
            k_scatB<0>  <<<NB, 1024, 0, stream>>>(x, cnt, grpsum, starts,
                                                  nullptr, xs, npts);
            k_main<0>   <<<NBUCKET, 512, 0, stream>>>(xs, x, nullptr, starts,
                                                      tab, (float4*)d_out);
            return;
        }
    }

    // ---- Tier B: perm-only payload (~8.5 MB ws) ----
    {
        size_t need = off_pay + (size_t)npts * 4;
        if (ws_size >= need) {
            unsigned* grpsum = (unsigned*)((char*)d_ws + off_grpsum);
            unsigned* cnt    = (unsigned*)((char*)d_ws + off_cnt);
            unsigned* starts = (unsigned*)((char*)d_ws + off_starts);
            unsigned* perm   = (unsigned*)((char*)d_ws + off_pay);

            hipMemsetAsync(grpsum, 0, (size_t)NGRP * NBUCKET * 4, stream);
            k_histA     <<<NB, 1024, 0, stream>>>(x, cnt, grpsum, npts);
            k_scatB<1>  <<<NB, 1024, 0, stream>>>(x, cnt, grpsum, starts,
                                                  perm, nullptr, npts);
            k_main<1>   <<<NBUCKET, 512, 0, stream>>>(nullptr, x, perm, starts,
                                                      tab, (float4*)d_out);
            return;
        }
    }

    // ---- fallback ----
    int total = npts * 16;
    k_fallback<<<(total + 255) / 256, 256, 0, stream>>>(
        x, tab, (float2*)d_out, total);
}